// Round 8
// baseline (448.794 us; speedup 1.0000x reference)
//
#include <hip/hip_runtime.h>

#define N_NODES 100000
#define N_EDGES 1600000

typedef _Float16 half8 __attribute__((ext_vector_type(8)));
typedef float floatx4 __attribute__((ext_vector_type(4)));

// ---------------- CSR build ----------------
// pass1: single packed u64 atomic per edge: [count:24 | weight-sum fixed20:40]
// returned old count field = this edge's slot ticket within its node.

__global__ __launch_bounds__(256) void edge_pass1(const int* __restrict__ ei,
                                                  const float* __restrict__ ew,
                                                  unsigned long long* __restrict__ packed,
                                                  unsigned short* __restrict__ tickets) {
    int e = blockIdx.x * 256 + threadIdx.x;
    if (e >= N_EDGES) return;
    int col = ei[N_EDGES + e];
    unsigned fx = (unsigned)(ew[e] * 1048576.0f + 0.5f);
    unsigned long long old = atomicAdd(&packed[col], (1ULL << 40) | (unsigned long long)fx);
    tickets[e] = (unsigned short)(old >> 40);
}

__global__ __launch_bounds__(256) void node_pass(const unsigned long long* __restrict__ packed,
                                                 float* __restrict__ dis,
                                                 int* __restrict__ offs,
                                                 int* __restrict__ gcur,
                                                 int* __restrict__ cnt) {
    int j = blockIdx.x * 256 + threadIdx.x;
    int lane = threadIdx.x & 63;
    int c = 0;
    if (j < N_NODES) {
        unsigned long long v = packed[j];
        c = (int)(v >> 40);
        float deg = (float)(v & ((1ULL << 40) - 1)) * (1.0f / 1048576.0f);
        dis[j] = rsqrtf(deg + 1.0f);
        cnt[j] = c;
    }
    int s = c;
    #pragma unroll
    for (int off = 1; off < 64; off <<= 1) {
        int t = __shfl_up(s, off, 64);
        if (lane >= off) s += t;
    }
    int total = __shfl(s, 63, 64);
    int base = 0;
    if (lane == 0) base = atomicAdd(gcur, total);
    base = __shfl(base, 0, 64);
    if (j < N_NODES) offs[j] = base + (s - c);
}

// csr entry: [f16 weight bits sans sign :15 | src :17]
__global__ __launch_bounds__(256) void edge_pass2(const int* __restrict__ ei,
                                                  const float* __restrict__ ew,
                                                  const float* __restrict__ dis,
                                                  const int* __restrict__ offs,
                                                  const unsigned short* __restrict__ tickets,
                                                  unsigned* __restrict__ csr) {
    int e = blockIdx.x * 256 + threadIdx.x;
    if (e >= N_EDGES) return;
    int row = ei[e];
    int col = ei[N_EDGES + e];
    int slot = offs[col] + (int)tickets[e];
    float nw = dis[row] * ew[e] * dis[col];
    _Float16 h = (_Float16)nw;
    unsigned short hb;
    __builtin_memcpy(&hb, &h, 2);
    csr[slot] = ((unsigned)hb << 17) | (unsigned)row;
}

// ---------------- weight prep: Wt[col][k] = (f16)W[k][col], 4 matrices ----------------

__global__ __launch_bounds__(256) void prep_w(const float* __restrict__ W0,
                                              const float* __restrict__ W1,
                                              const float* __restrict__ W2,
                                              const float* __restrict__ W3,
                                              _Float16* __restrict__ Wt) {
    int m = blockIdx.x >> 4;
    const float* W = (m == 0) ? W0 : (m == 1) ? W1 : (m == 2) ? W2 : W3;
    _Float16* o = Wt + m * 16384;
    int base = (blockIdx.x & 15) * 1024 + threadIdx.x * 4;
    int col = base >> 7;
    int k0 = base & 127;
    #pragma unroll
    for (int i = 0; i < 4; i++) o[base + i] = (_Float16)W[(k0 + i) * 128 + col];
}

// ---------------- encoder layer 1: [N,16]@[16,128]+b, relu -> f16 ----------------

__global__ __launch_bounds__(256) void enc1_kernel(const float* __restrict__ x,
                                                   const float* __restrict__ W1,
                                                   const float* __restrict__ b1,
                                                   _Float16* __restrict__ out) {
    __shared__ float sX[256 * 17];
    __shared__ float sW[2048];
    __shared__ float sb[128];
    int t = threadIdx.x;
    int base = blockIdx.x * 256;
    for (int i = t; i < 512; i += 256) ((float4*)sW)[i] = ((const float4*)W1)[i];
    if (t < 128) sb[t] = b1[t];
    #pragma unroll
    for (int i = 0; i < 4; i++) {
        int f = i * 1024 + t * 4;
        int row = f >> 4, k = f & 15;
        float4 v = make_float4(0.f, 0.f, 0.f, 0.f);
        if (base + row < N_NODES) v = *(const float4*)(x + (size_t)(base + row) * 16 + k);
        *(float4*)(sX + row * 17 + k) = v;
    }
    __syncthreads();
    int row = base + t;
    if (row >= N_NODES) return;
    float xr[16];
    #pragma unroll
    for (int k = 0; k < 16; k++) xr[k] = sX[t * 17 + k];
    #pragma unroll 4
    for (int cb = 0; cb < 16; cb++) {
        float acc[8];
        #pragma unroll
        for (int jj = 0; jj < 8; jj++) acc[jj] = sb[cb * 8 + jj];
        #pragma unroll
        for (int k = 0; k < 16; k++) {
            float xv = xr[k];
            #pragma unroll
            for (int jj = 0; jj < 8; jj++) acc[jj] = fmaf(xv, sW[k * 128 + cb * 8 + jj], acc[jj]);
        }
        half8 h;
        #pragma unroll
        for (int jj = 0; jj < 8; jj++) h[jj] = (_Float16)fmaxf(acc[jj], 0.f);
        *(half8*)(out + (size_t)row * 128 + cb * 8) = h;
    }
}

// ---------------- f16 MFMA GEMM: [N,128] @ [128,128], 2-phase pipelined ----------------
// Double-buffered sA; next tile's global_load_lds issued before current compute;
// counted vmcnt + raw s_barrier (no full drain).

#define GEMM_GRID 522

template <bool BIAS, bool RELU, bool DEC>
__global__ __launch_bounds__(256, 2) void gemm_mfma(const _Float16* __restrict__ A,
                                                    const _Float16* __restrict__ Wt,
                                                    const float* __restrict__ bias,
                                                    _Float16* __restrict__ C,
                                                    const float* __restrict__ W2,
                                                    const float* __restrict__ b2,
                                                    float* __restrict__ sm_out) {
    __shared__ _Float16 sA[2 * 64 * 128];     // 32 KB double buffer
    __shared__ _Float16 sE[DEC ? 64 : 64 * 128];
    __shared__ float sW2[DEC ? 256 : 1];
    int t = threadIdx.x;
    int lane = t & 63;
    int w = t >> 6;
    int l15 = lane & 15;
    int l4 = lane >> 4;

    half8 bfrag[8][4];
    #pragma unroll
    for (int n = 0; n < 8; n++)
        #pragma unroll
        for (int kk = 0; kk < 4; kk++)
            bfrag[n][kk] = *(const half8*)(Wt + (n * 16 + l15) * 128 + kk * 32 + l4 * 8);

    float bcol[8];
    if constexpr (BIAS) {
        #pragma unroll
        for (int n = 0; n < 8; n++) bcol[n] = bias[n * 16 + l15];
    }
    float b20 = 0.f, b21 = 0.f;
    if constexpr (DEC) {
        if (t < 256) sW2[t] = W2[t];
        b20 = b2[0]; b21 = b2[1];
    }

    auto STAGE = [&](int buf, int tile) {
        const _Float16* Ag = A + (size_t)tile * 64 * 128;
        #pragma unroll
        for (int i = 0; i < 4; i++) {
            int c = i * 256 + t;
            int row = c >> 4;
            int g = (c & 15) ^ (row & 7);
            const _Float16* src = Ag + row * 128 + g * 8;
            __builtin_amdgcn_global_load_lds(
                (const __attribute__((address_space(1))) void*)src,
                (__attribute__((address_space(3))) void*)(sA + buf * 8192 + (size_t)(i * 256 + w * 64) * 8),
                16, 0, 0);
        }
    };

    const int NT = (N_NODES + 63) / 64;
    int cur = 0;
    STAGE(0, blockIdx.x);

    for (int tile = blockIdx.x; tile < NT; tile += GEMM_GRID) {
        int nx = tile + GEMM_GRID;
        if (nx < NT) {
            STAGE(cur ^ 1, nx);
            asm volatile("s_waitcnt vmcnt(4)" ::: "memory");
        } else {
            asm volatile("s_waitcnt vmcnt(0)" ::: "memory");
        }
        __builtin_amdgcn_s_barrier();
        asm volatile("" ::: "memory");

        const _Float16* sAc = sA + cur * 8192;

        floatx4 acc[8];
        #pragma unroll
        for (int n = 0; n < 8; n++) acc[n] = (floatx4)(0.f);

        #pragma unroll
        for (int kk = 0; kk < 4; kk++) {
            int rloc = w * 16 + l15;
            int cl = kk * 4 + l4;
            int s = cl ^ (rloc & 7);
            half8 af = *(const half8*)(sAc + rloc * 128 + s * 8);
            #pragma unroll
            for (int n = 0; n < 8; n++)
                acc[n] = __builtin_amdgcn_mfma_f32_16x16x32_f16(af, bfrag[n][kk], acc[n], 0, 0, 0);
        }

        size_t base_row = (size_t)tile * 64;
        if constexpr (DEC) {
            #pragma unroll
            for (int r = 0; r < 4; r++) {
                float p0 = 0.f, p1 = 0.f;
                #pragma unroll
                for (int n = 0; n < 8; n++) {
                    float v = acc[n][r];
                    if constexpr (BIAS) v += bcol[n];
                    if constexpr (RELU) v = fmaxf(v, 0.f);
                    int ch = n * 16 + l15;
                    p0 = fmaf(v, sW2[ch * 2 + 0], p0);
                    p1 = fmaf(v, sW2[ch * 2 + 1], p1);
                }
                #pragma unroll
                for (int m = 1; m < 16; m <<= 1) {
                    p0 += __shfl_xor(p0, m, 64);
                    p1 += __shfl_xor(p1, m, 64);
                }
                size_t grow = base_row + w * 16 + l4 * 4 + r;
                if (l15 == 0 && grow < N_NODES) {
                    float z0 = p0 + b20, z1 = p1 + b21;
                    float mx = fmaxf(z0, z1);
                    float e0 = expf(z0 - mx), e1 = expf(z1 - mx);
                    float si = 1.f / (e0 + e1);
                    *(float2*)(sm_out + grow * 2) = make_float2(e0 * si, e1 * si);
                }
            }
            __builtin_amdgcn_s_barrier();
            asm volatile("" ::: "memory");
        } else {
            #pragma unroll
            for (int n = 0; n < 8; n++) {
                #pragma unroll
                for (int r = 0; r < 4; r++) {
                    float v = acc[n][r];
                    if constexpr (BIAS) v += bcol[n];
                    if constexpr (RELU) v = fmaxf(v, 0.f);
                    int row = w * 16 + l4 * 4 + r;
                    sE[row * 128 + n * 16 + l15] = (_Float16)v;
                }
            }
            __builtin_amdgcn_s_barrier();
            asm volatile("" ::: "memory");
            #pragma unroll
            for (int i = 0; i < 4; i++) {
                int c = i * 256 + t;
                int row = c >> 4;
                if (base_row + row < N_NODES) {
                    *(float4*)((char*)C + (base_row + row) * 256 + (c & 15) * 16) =
                        *(const float4*)((const char*)sE + (size_t)c * 16);
                }
            }
        }
        cur ^= 1;
    }
}

// ---------------- GCN aggregation: 16 edges in flight ----------------
// Wave = 4 groups x 16 lanes. Group g owns edges e+g, e+4+g, e+8+g, e+12+g;
// lane q owns 8-channel chunk (half8, 16B gather). Cross-group shfl_xor reduce.

__device__ __forceinline__ float wdec(unsigned u) {
    unsigned short b = (unsigned short)(u >> 17);
    _Float16 h;
    __builtin_memcpy(&h, &b, 2);
    return (float)h;
}

__global__ __launch_bounds__(256) void agg_kernel(const _Float16* __restrict__ m,
                                                  const int* __restrict__ offs,
                                                  const int* __restrict__ cnt,
                                                  const unsigned* __restrict__ csr,
                                                  const float* __restrict__ dis,
                                                  const float* __restrict__ bias,
                                                  _Float16* __restrict__ out) {
    int wave = threadIdx.x >> 6;
    int lane = threadIdx.x & 63;
    int g = lane >> 4;
    int q = lane & 15;
    int j = blockIdx.x * 4 + wave;
    if (j >= N_NODES) return;
    int s = offs[j];
    int num = cnt[j];

    float acc[8];
    if (g == 0) {
        float d = dis[j];
        float dd = d * d;
        half8 mv = *(const half8*)(m + (size_t)j * 128 + q * 8);
        #pragma unroll
        for (int i = 0; i < 8; i++) acc[i] = dd * (float)mv[i];
    } else {
        #pragma unroll
        for (int i = 0; i < 8; i++) acc[i] = 0.f;
    }

    int e = 0;
    for (; e + 16 <= num; e += 16) {
        unsigned u0 = csr[s + e + g];
        unsigned u1 = csr[s + e + 4 + g];
        unsigned u2 = csr[s + e + 8 + g];
        unsigned u3 = csr[s + e + 12 + g];
        half8 r0 = *(const half8*)(m + (size_t)(u0 & 0x1FFFF) * 128 + q * 8);
        half8 r1 = *(const half8*)(m + (size_t)(u1 & 0x1FFFF) * 128 + q * 8);
        half8 r2 = *(const half8*)(m + (size_t)(u2 & 0x1FFFF) * 128 + q * 8);
        half8 r3 = *(const half8*)(m + (size_t)(u3 & 0x1FFFF) * 128 + q * 8);
        float w0 = wdec(u0), w1 = wdec(u1), w2 = wdec(u2), w3 = wdec(u3);
        #pragma unroll
        for (int i = 0; i < 8; i++) acc[i] = fmaf(w0, (float)r0[i], acc[i]);
        #pragma unroll
        for (int i = 0; i < 8; i++) acc[i] = fmaf(w1, (float)r1[i], acc[i]);
        #pragma unroll
        for (int i = 0; i < 8; i++) acc[i] = fmaf(w2, (float)r2[i], acc[i]);
        #pragma unroll
        for (int i = 0; i < 8; i++) acc[i] = fmaf(w3, (float)r3[i], acc[i]);
    }
    for (; e < num; e += 4) {
        if (e + g < num) {
            unsigned u0 = csr[s + e + g];
            half8 r0 = *(const half8*)(m + (size_t)(u0 & 0x1FFFF) * 128 + q * 8);
            float w0 = wdec(u0);
            #pragma unroll
            for (int i = 0; i < 8; i++) acc[i] = fmaf(w0, (float)r0[i], acc[i]);
        }
    }

    #pragma unroll
    for (int i = 0; i < 8; i++) {
        acc[i] += __shfl_xor(acc[i], 16, 64);
        acc[i] += __shfl_xor(acc[i], 32, 64);
    }

    if (g == 0) {
        float4 b0 = *(const float4*)(bias + q * 8);
        float4 b1 = *(const float4*)(bias + q * 8 + 4);
        float bb[8] = {b0.x, b0.y, b0.z, b0.w, b1.x, b1.y, b1.z, b1.w};
        half8 o;
        #pragma unroll
        for (int i = 0; i < 8; i++) o[i] = (_Float16)fmaxf(acc[i] + bb[i], 0.f);
        *(half8*)(out + (size_t)j * 128 + q * 8) = o;
    }
}

// ---------------- launch ----------------

extern "C" void kernel_launch(void* const* d_in, const int* in_sizes, int n_in,
                              void* d_out, int out_size, void* d_ws, size_t ws_size,
                              hipStream_t stream) {
    const float* x      = (const float*)d_in[0];
    const int*   ei     = (const int*)d_in[1];
    const float* ew     = (const float*)d_in[2];
    const float* enc_W1 = (const float*)d_in[3];
    const float* enc_b1 = (const float*)d_in[4];
    const float* enc_W2 = (const float*)d_in[5];
    const float* enc_b2 = (const float*)d_in[6];
    const float* c1_W   = (const float*)d_in[7];
    const float* c1_b   = (const float*)d_in[8];
    const float* c2_W   = (const float*)d_in[9];
    const float* c2_b   = (const float*)d_in[10];
    const float* dec_W1 = (const float*)d_in[11];
    const float* dec_b1 = (const float*)d_in[12];
    const float* dec_W2 = (const float*)d_in[13];
    const float* dec_b2 = (const float*)d_in[14];
    float* out = (float*)d_out;

    char* ws = (char*)d_ws;
    _Float16* B1 = (_Float16*)(ws);                          // 25,600,000
    _Float16* B2 = (_Float16*)(ws + 25600000);               // 25,600,000
    _Float16* Wt = (_Float16*)(ws + 51200000);               // 131,072
    unsigned long long* packed = (unsigned long long*)(ws + 51331072);  // 800,000
    int*   gcur    = (int*)  (ws + 52131072);                // 256
    float* dis     = (float*)(ws + 52131328);                // 400,000
    int*   offs    = (int*)  (ws + 52531328);                // 400,000
    int*   cnt     = (int*)  (ws + 52931328);                // 400,000
    unsigned short* tickets = (unsigned short*)(ws + 53331328); // 3,200,000
    unsigned* csr  = (unsigned*)(ws + 56531328);             // 6,400,000
    // end ~62.9 MB

    // zero packed + gcur (contiguous)
    hipMemsetAsync(packed, 0, 800256, stream);

    edge_pass1<<<(N_EDGES + 255) / 256, 256, 0, stream>>>(ei, ew, packed, tickets);
    node_pass<<<(N_NODES + 255) / 256, 256, 0, stream>>>(packed, dis, offs, gcur, cnt);
    edge_pass2<<<(N_EDGES + 255) / 256, 256, 0, stream>>>(ei, ew, dis, offs, tickets, csr);

    prep_w<<<64, 256, 0, stream>>>(enc_W2, c1_W, c2_W, dec_W1, Wt);
    enc1_kernel<<<(N_NODES + 255) / 256, 256, 0, stream>>>(x, enc_W1, enc_b1, B1);

    gemm_mfma<true, false, false><<<GEMM_GRID, 256, 0, stream>>>(B1, Wt + 0 * 16384, enc_b2, B2, nullptr, nullptr, nullptr);
    gemm_mfma<false, false, false><<<GEMM_GRID, 256, 0, stream>>>(B2, Wt + 1 * 16384, nullptr, B1, nullptr, nullptr, nullptr);
    agg_kernel<<<N_NODES / 4, 256, 0, stream>>>(B1, offs, cnt, csr, dis, c1_b, B2);
    gemm_mfma<false, false, false><<<GEMM_GRID, 256, 0, stream>>>(B2, Wt + 2 * 16384, nullptr, B1, nullptr, nullptr, nullptr);
    agg_kernel<<<N_NODES / 4, 256, 0, stream>>>(B1, offs, cnt, csr, dis, c2_b, B2);
    gemm_mfma<true, true, true><<<GEMM_GRID, 256, 0, stream>>>(B2, Wt + 3 * 16384, dec_b1, nullptr, dec_W2, dec_b2, out);
}

// Round 10
// 384.489 us; speedup vs baseline: 1.1672x; 1.1672x over previous
//
#include <hip/hip_runtime.h>

#define N_NODES 100000
#define N_EDGES 1600000
#define NBKT 391          // ceil(100000/256) buckets of 256 nodes
#define BKT_CAP 4608      // padded bucket capacity (avg 4096, +8 sigma)
#define PART_BLOCKS 391   // k_part blocks, 4096 edges each

typedef _Float16 half8 __attribute__((ext_vector_type(8)));
typedef float floatx4 __attribute__((ext_vector_type(4)));

// ---------------- atomic-light CSR build ----------------
// k_part: partition edges into 391 coarse buckets (col>>8); one global atomic
// per (block,bucket) = 153K atomics on 391 hot addresses.
// partA u32 = [cl:8 bits 17..24 | row:17 bits 0..16]; partB = f32 ew.

__global__ __launch_bounds__(256) void k_part(const int* __restrict__ ei,
                                              const float* __restrict__ ew,
                                              unsigned* __restrict__ cursor,
                                              unsigned* __restrict__ partA,
                                              float* __restrict__ partB) {
    __shared__ unsigned hist[NBKT];
    __shared__ unsigned lrank[NBKT];
    __shared__ unsigned basebuf[NBKT];
    int tid = threadIdx.x;
    int e0 = blockIdx.x * 4096 + tid * 16;
    for (int i = tid; i < NBKT; i += 256) { hist[i] = 0; lrank[i] = 0; }
    __syncthreads();

    unsigned bk[16];
    bool full = (e0 + 16 <= N_EDGES);
    if (full) {
        #pragma unroll
        for (int v = 0; v < 4; v++) {
            int4 c = *(const int4*)(ei + N_EDGES + e0 + v * 4);
            bk[v * 4 + 0] = (unsigned)c.x >> 8;
            bk[v * 4 + 1] = (unsigned)c.y >> 8;
            bk[v * 4 + 2] = (unsigned)c.z >> 8;
            bk[v * 4 + 3] = (unsigned)c.w >> 8;
        }
        #pragma unroll
        for (int i = 0; i < 16; i++) atomicAdd(&hist[bk[i]], 1u);
    } else {
        for (int i = 0; i < 16; i++) {
            if (e0 + i < N_EDGES) {
                bk[i] = (unsigned)ei[N_EDGES + e0 + i] >> 8;
                atomicAdd(&hist[bk[i]], 1u);
            }
        }
    }
    __syncthreads();
    for (int b = tid; b < NBKT; b += 256) {
        unsigned h = hist[b];
        basebuf[b] = h ? atomicAdd(&cursor[b], h) : 0u;
    }
    __syncthreads();

    if (full) {
        #pragma unroll
        for (int v = 0; v < 4; v++) {
            int4 c = *(const int4*)(ei + N_EDGES + e0 + v * 4);
            int4 r = *(const int4*)(ei + e0 + v * 4);
            float4 w = *(const float4*)(ew + e0 + v * 4);
            int cols[4] = {c.x, c.y, c.z, c.w};
            int rows[4] = {r.x, r.y, r.z, r.w};
            float ws4[4] = {w.x, w.y, w.z, w.w};
            #pragma unroll
            for (int i = 0; i < 4; i++) {
                unsigned b = bk[v * 4 + i];
                unsigned rk = atomicAdd(&lrank[b], 1u);
                size_t idx = (size_t)b * BKT_CAP + basebuf[b] + rk;
                partA[idx] = (((unsigned)cols[i] & 255u) << 17) | (unsigned)rows[i];
                partB[idx] = ws4[i];
            }
        }
    } else {
        for (int i = 0; i < 16; i++) {
            if (e0 + i < N_EDGES) {
                int col = ei[N_EDGES + e0 + i];
                int row = ei[e0 + i];
                float wv = ew[e0 + i];
                unsigned b = bk[i];
                unsigned rk = atomicAdd(&lrank[b], 1u);
                size_t idx = (size_t)b * BKT_CAP + basebuf[b] + rk;
                partA[idx] = (((unsigned)col & 255u) << 17) | (unsigned)row;
                partB[idx] = wv;
            }
        }
    }
}

// k_stats: per-bucket histogram + weighted degree + prefix scan -> dis/offs/cnt.

__global__ __launch_bounds__(256) void k_stats(const unsigned* __restrict__ cursor,
                                               const unsigned* __restrict__ partA,
                                               const float* __restrict__ partB,
                                               float* __restrict__ dis,
                                               int* __restrict__ offs,
                                               int* __restrict__ cnt) {
    __shared__ unsigned hist[256];
    __shared__ unsigned sc[256];
    __shared__ float dacc[256];
    int tid = threadIdx.x;
    int j = blockIdx.x;
    int count = (int)cursor[j];
    size_t p0 = (size_t)j * BKT_CAP;
    hist[tid] = 0;
    dacc[tid] = 0.f;
    __syncthreads();
    for (int i = tid; i < count; i += 256) {
        unsigned a = partA[p0 + i];
        float w = partB[p0 + i];
        unsigned cl = (a >> 17) & 255u;
        atomicAdd(&hist[cl], 1u);
        atomicAdd(&dacc[cl], w);
    }
    __syncthreads();
    unsigned myc = hist[tid];
    sc[tid] = myc;
    __syncthreads();
    #pragma unroll
    for (int d = 1; d < 256; d <<= 1) {
        unsigned t = (tid >= d) ? sc[tid - d] : 0u;
        __syncthreads();
        sc[tid] += t;
        __syncthreads();
    }
    int col = j * 256 + tid;
    if (col < N_NODES) {
        dis[col] = rsqrtf(dacc[tid] + 1.0f);
        cnt[col] = (int)myc;
        offs[col] = (int)(p0 + (sc[tid] - myc));
    }
}

// k_scatter: per-bucket LDS-cursor scatter; csr entry [f16 w sans sign:15 | row:17]

__global__ __launch_bounds__(256) void k_scatter(const unsigned* __restrict__ cursor,
                                                 const unsigned* __restrict__ partA,
                                                 const float* __restrict__ partB,
                                                 const int* __restrict__ offs,
                                                 const float* __restrict__ dis,
                                                 unsigned* __restrict__ csr) {
    __shared__ unsigned cur[256];
    int tid = threadIdx.x;
    int j = blockIdx.x;
    int count = (int)cursor[j];
    size_t p0 = (size_t)j * BKT_CAP;
    int col = j * 256 + tid;
    cur[tid] = (col < N_NODES) ? (unsigned)(offs[col] - (int)p0) : 0u;
    __syncthreads();
    for (int i = tid; i < count; i += 256) {
        unsigned a = partA[p0 + i];
        float wv = partB[p0 + i];
        unsigned cl = (a >> 17) & 255u;
        unsigned row = a & 0x1FFFFu;
        unsigned r = atomicAdd(&cur[cl], 1u);
        int colg = j * 256 + (int)cl;
        float w = dis[row] * wv * dis[colg];
        _Float16 hw = (_Float16)w;
        unsigned short hb;
        __builtin_memcpy(&hb, &hw, 2);
        csr[p0 + r] = ((unsigned)hb << 17) | row;
    }
}

// ---------------- weight prep: Wt[col][k] = (f16)W[k][col], 4 matrices ----------------

__global__ __launch_bounds__(256) void prep_w(const float* __restrict__ W0,
                                              const float* __restrict__ W1,
                                              const float* __restrict__ W2,
                                              const float* __restrict__ W3,
                                              _Float16* __restrict__ Wt) {
    int m = blockIdx.x >> 4;
    const float* W = (m == 0) ? W0 : (m == 1) ? W1 : (m == 2) ? W2 : W3;
    _Float16* o = Wt + m * 16384;
    int base = (blockIdx.x & 15) * 1024 + threadIdx.x * 4;
    int col = base >> 7;
    int k0 = base & 127;
    #pragma unroll
    for (int i = 0; i < 4; i++) o[base + i] = (_Float16)W[(k0 + i) * 128 + col];
}

// ---------------- encoder layer 1: [N,16]@[16,128]+b, relu -> f16 ----------------

__global__ __launch_bounds__(256) void enc1_kernel(const float* __restrict__ x,
                                                   const float* __restrict__ W1,
                                                   const float* __restrict__ b1,
                                                   _Float16* __restrict__ out) {
    __shared__ float sX[256 * 17];
    __shared__ float sW[2048];
    __shared__ float sb[128];
    int t = threadIdx.x;
    int base = blockIdx.x * 256;
    for (int i = t; i < 512; i += 256) ((float4*)sW)[i] = ((const float4*)W1)[i];
    if (t < 128) sb[t] = b1[t];
    #pragma unroll
    for (int i = 0; i < 4; i++) {
        int f = i * 1024 + t * 4;
        int row = f >> 4, k = f & 15;
        float4 v = make_float4(0.f, 0.f, 0.f, 0.f);
        if (base + row < N_NODES) v = *(const float4*)(x + (size_t)(base + row) * 16 + k);
        *(float4*)(sX + row * 17 + k) = v;
    }
    __syncthreads();
    int row = base + t;
    if (row >= N_NODES) return;
    float xr[16];
    #pragma unroll
    for (int k = 0; k < 16; k++) xr[k] = sX[t * 17 + k];
    #pragma unroll 4
    for (int cb = 0; cb < 16; cb++) {
        float acc[8];
        #pragma unroll
        for (int jj = 0; jj < 8; jj++) acc[jj] = sb[cb * 8 + jj];
        #pragma unroll
        for (int k = 0; k < 16; k++) {
            float xv = xr[k];
            #pragma unroll
            for (int jj = 0; jj < 8; jj++) acc[jj] = fmaf(xv, sW[k * 128 + cb * 8 + jj], acc[jj]);
        }
        half8 h;
        #pragma unroll
        for (int jj = 0; jj < 8; jj++) h[jj] = (_Float16)fmaxf(acc[jj], 0.f);
        *(half8*)(out + (size_t)row * 128 + cb * 8) = h;
    }
}

// ---------------- f16 MFMA GEMM: [N,128] @ [128,128], 2-phase pipelined ----------------

#define GEMM_GRID 522

template <bool BIAS, bool RELU, bool DEC>
__global__ __launch_bounds__(256, 2) void gemm_mfma(const _Float16* __restrict__ A,
                                                    const _Float16* __restrict__ Wt,
                                                    const float* __restrict__ bias,
                                                    _Float16* __restrict__ C,
                                                    const float* __restrict__ W2,
                                                    const float* __restrict__ b2,
                                                    float* __restrict__ sm_out) {
    __shared__ _Float16 sA[2 * 64 * 128];
    __shared__ _Float16 sE[DEC ? 64 : 64 * 128];
    __shared__ float sW2[DEC ? 256 : 1];
    int t = threadIdx.x;
    int lane = t & 63;
    int w = t >> 6;
    int l15 = lane & 15;
    int l4 = lane >> 4;

    half8 bfrag[8][4];
    #pragma unroll
    for (int n = 0; n < 8; n++)
        #pragma unroll
        for (int kk = 0; kk < 4; kk++)
            bfrag[n][kk] = *(const half8*)(Wt + (n * 16 + l15) * 128 + kk * 32 + l4 * 8);

    float bcol[8];
    if constexpr (BIAS) {
        #pragma unroll
        for (int n = 0; n < 8; n++) bcol[n] = bias[n * 16 + l15];
    }
    float b20 = 0.f, b21 = 0.f;
    if constexpr (DEC) {
        if (t < 256) sW2[t] = W2[t];
        b20 = b2[0]; b21 = b2[1];
    }

    auto STAGE = [&](int buf, int tile) {
        const _Float16* Ag = A + (size_t)tile * 64 * 128;
        #pragma unroll
        for (int i = 0; i < 4; i++) {
            int c = i * 256 + t;
            int row = c >> 4;
            int g = (c & 15) ^ (row & 7);
            const _Float16* src = Ag + row * 128 + g * 8;
            __builtin_amdgcn_global_load_lds(
                (const __attribute__((address_space(1))) void*)src,
                (__attribute__((address_space(3))) void*)(sA + buf * 8192 + (size_t)(i * 256 + w * 64) * 8),
                16, 0, 0);
        }
    };

    const int NT = (N_NODES + 63) / 64;
    int cur = 0;
    STAGE(0, blockIdx.x);

    for (int tile = blockIdx.x; tile < NT; tile += GEMM_GRID) {
        int nx = tile + GEMM_GRID;
        if (nx < NT) {
            STAGE(cur ^ 1, nx);
            asm volatile("s_waitcnt vmcnt(4)" ::: "memory");
        } else {
            asm volatile("s_waitcnt vmcnt(0)" ::: "memory");
        }
        __builtin_amdgcn_s_barrier();
        asm volatile("" ::: "memory");

        const _Float16* sAc = sA + cur * 8192;

        floatx4 acc[8];
        #pragma unroll
        for (int n = 0; n < 8; n++) acc[n] = (floatx4)(0.f);

        #pragma unroll
        for (int kk = 0; kk < 4; kk++) {
            int rloc = w * 16 + l15;
            int cl = kk * 4 + l4;
            int s = cl ^ (rloc & 7);
            half8 af = *(const half8*)(sAc + rloc * 128 + s * 8);
            #pragma unroll
            for (int n = 0; n < 8; n++)
                acc[n] = __builtin_amdgcn_mfma_f32_16x16x32_f16(af, bfrag[n][kk], acc[n], 0, 0, 0);
        }

        size_t base_row = (size_t)tile * 64;
        if constexpr (DEC) {
            #pragma unroll
            for (int r = 0; r < 4; r++) {
                float p0 = 0.f, p1 = 0.f;
                #pragma unroll
                for (int n = 0; n < 8; n++) {
                    float v = acc[n][r];
                    if constexpr (BIAS) v += bcol[n];
                    if constexpr (RELU) v = fmaxf(v, 0.f);
                    int ch = n * 16 + l15;
                    p0 = fmaf(v, sW2[ch * 2 + 0], p0);
                    p1 = fmaf(v, sW2[ch * 2 + 1], p1);
                }
                #pragma unroll
                for (int m = 1; m < 16; m <<= 1) {
                    p0 += __shfl_xor(p0, m, 64);
                    p1 += __shfl_xor(p1, m, 64);
                }
                size_t grow = base_row + w * 16 + l4 * 4 + r;
                if (l15 == 0 && grow < N_NODES) {
                    float z0 = p0 + b20, z1 = p1 + b21;
                    float mx = fmaxf(z0, z1);
                    float e0 = expf(z0 - mx), e1 = expf(z1 - mx);
                    float si = 1.f / (e0 + e1);
                    *(float2*)(sm_out + grow * 2) = make_float2(e0 * si, e1 * si);
                }
            }
            __builtin_amdgcn_s_barrier();
            asm volatile("" ::: "memory");
        } else {
            #pragma unroll
            for (int n = 0; n < 8; n++) {
                #pragma unroll
                for (int r = 0; r < 4; r++) {
                    float v = acc[n][r];
                    if constexpr (BIAS) v += bcol[n];
                    if constexpr (RELU) v = fmaxf(v, 0.f);
                    int row = w * 16 + l4 * 4 + r;
                    sE[row * 128 + n * 16 + l15] = (_Float16)v;
                }
            }
            __builtin_amdgcn_s_barrier();
            asm volatile("" ::: "memory");
            #pragma unroll
            for (int i = 0; i < 4; i++) {
                int c = i * 256 + t;
                int row = c >> 4;
                if (base_row + row < N_NODES) {
                    *(float4*)((char*)C + (base_row + row) * 256 + (c & 15) * 16) =
                        *(const float4*)((const char*)sE + (size_t)c * 16);
                }
            }
        }
        cur ^= 1;
    }
}

// ---------------- GCN aggregation: 16 edges in flight ----------------

__device__ __forceinline__ float wdec(unsigned u) {
    unsigned short b = (unsigned short)(u >> 17);
    _Float16 h;
    __builtin_memcpy(&h, &b, 2);
    return (float)h;
}

__global__ __launch_bounds__(256) void agg_kernel(const _Float16* __restrict__ m,
                                                  const int* __restrict__ offs,
                                                  const int* __restrict__ cnt,
                                                  const unsigned* __restrict__ csr,
                                                  const float* __restrict__ dis,
                                                  const float* __restrict__ bias,
                                                  _Float16* __restrict__ out) {
    int wave = threadIdx.x >> 6;
    int lane = threadIdx.x & 63;
    int g = lane >> 4;
    int q = lane & 15;
    int j = blockIdx.x * 4 + wave;
    if (j >= N_NODES) return;
    int s = offs[j];
    int num = cnt[j];

    float acc[8];
    if (g == 0) {
        float d = dis[j];
        float dd = d * d;
        half8 mv = *(const half8*)(m + (size_t)j * 128 + q * 8);
        #pragma unroll
        for (int i = 0; i < 8; i++) acc[i] = dd * (float)mv[i];
    } else {
        #pragma unroll
        for (int i = 0; i < 8; i++) acc[i] = 0.f;
    }

    int e = 0;
    for (; e + 16 <= num; e += 16) {
        unsigned u0 = csr[s + e + g];
        unsigned u1 = csr[s + e + 4 + g];
        unsigned u2 = csr[s + e + 8 + g];
        unsigned u3 = csr[s + e + 12 + g];
        half8 r0 = *(const half8*)(m + (size_t)(u0 & 0x1FFFF) * 128 + q * 8);
        half8 r1 = *(const half8*)(m + (size_t)(u1 & 0x1FFFF) * 128 + q * 8);
        half8 r2 = *(const half8*)(m + (size_t)(u2 & 0x1FFFF) * 128 + q * 8);
        half8 r3 = *(const half8*)(m + (size_t)(u3 & 0x1FFFF) * 128 + q * 8);
        float w0 = wdec(u0), w1 = wdec(u1), w2 = wdec(u2), w3 = wdec(u3);
        #pragma unroll
        for (int i = 0; i < 8; i++) acc[i] = fmaf(w0, (float)r0[i], acc[i]);
        #pragma unroll
        for (int i = 0; i < 8; i++) acc[i] = fmaf(w1, (float)r1[i], acc[i]);
        #pragma unroll
        for (int i = 0; i < 8; i++) acc[i] = fmaf(w2, (float)r2[i], acc[i]);
        #pragma unroll
        for (int i = 0; i < 8; i++) acc[i] = fmaf(w3, (float)r3[i], acc[i]);
    }
    for (; e < num; e += 4) {
        if (e + g < num) {
            unsigned u0 = csr[s + e + g];
            half8 r0 = *(const half8*)(m + (size_t)(u0 & 0x1FFFF) * 128 + q * 8);
            float w0 = wdec(u0);
            #pragma unroll
            for (int i = 0; i < 8; i++) acc[i] = fmaf(w0, (float)r0[i], acc[i]);
        }
    }

    #pragma unroll
    for (int i = 0; i < 8; i++) {
        acc[i] += __shfl_xor(acc[i], 16, 64);
        acc[i] += __shfl_xor(acc[i], 32, 64);
    }

    if (g == 0) {
        float4 b0 = *(const float4*)(bias + q * 8);
        float4 b1 = *(const float4*)(bias + q * 8 + 4);
        float bb[8] = {b0.x, b0.y, b0.z, b0.w, b1.x, b1.y, b1.z, b1.w};
        half8 o;
        #pragma unroll
        for (int i = 0; i < 8; i++) o[i] = (_Float16)fmaxf(acc[i] + bb[i], 0.f);
        *(half8*)(out + (size_t)j * 128 + q * 8) = o;
    }
}

// ---------------- launch ----------------

extern "C" void kernel_launch(void* const* d_in, const int* in_sizes, int n_in,
                              void* d_out, int out_size, void* d_ws, size_t ws_size,
                              hipStream_t stream) {
    const float* x      = (const float*)d_in[0];
    const int*   ei     = (const int*)d_in[1];
    const float* ew     = (const float*)d_in[2];
    const float* enc_W1 = (const float*)d_in[3];
    const float* enc_b1 = (const float*)d_in[4];
    const float* enc_W2 = (const float*)d_in[5];
    const float* enc_b2 = (const float*)d_in[6];
    const float* c1_W   = (const float*)d_in[7];
    const float* c1_b   = (const float*)d_in[8];
    const float* c2_W   = (const float*)d_in[9];
    const float* c2_b   = (const float*)d_in[10];
    const float* dec_W1 = (const float*)d_in[11];
    const float* dec_b1 = (const float*)d_in[12];
    const float* dec_W2 = (const float*)d_in[13];
    const float* dec_b2 = (const float*)d_in[14];
    float* out = (float*)d_out;

    char* ws = (char*)d_ws;
    // part buffers alias B1 (dead before enc1 writes B1)
    unsigned* partA = (unsigned*)(ws);                       // 7,206,912
    float*    partB = (float*)(ws + 7206912);                // 7,206,912 (ends 14,413,824)
    _Float16* B1 = (_Float16*)(ws);                          // 25,600,000
    _Float16* B2 = (_Float16*)(ws + 25600000);               // 25,600,000
    _Float16* Wt = (_Float16*)(ws + 51200000);               // 131,072
    unsigned* cursor = (unsigned*)(ws + 51331072);           // 2,048
    float* dis     = (float*)(ws + 51333120);                // 400,000
    int*   offs    = (int*)  (ws + 51733120);                // 400,000
    int*   cnt     = (int*)  (ws + 52133120);                // 400,000
    unsigned* csr  = (unsigned*)(ws + 52533120);             // 7,206,912
    // end 59,740,032 (~59.7 MB)

    hipMemsetAsync(cursor, 0, 2048, stream);

    k_part<<<PART_BLOCKS, 256, 0, stream>>>(ei, ew, cursor, partA, partB);
    k_stats<<<NBKT, 256, 0, stream>>>(cursor, partA, partB, dis, offs, cnt);
    k_scatter<<<NBKT, 256, 0, stream>>>(cursor, partA, partB, offs, dis, csr);

    prep_w<<<64, 256, 0, stream>>>(enc_W2, c1_W, c2_W, dec_W1, Wt);
    enc1_kernel<<<(N_NODES + 255) / 256, 256, 0, stream>>>(x, enc_W1, enc_b1, B1);

    gemm_mfma<true, false, false><<<GEMM_GRID, 256, 0, stream>>>(B1, Wt + 0 * 16384, enc_b2, B2, nullptr, nullptr, nullptr);
    gemm_mfma<false, false, false><<<GEMM_GRID, 256, 0, stream>>>(B2, Wt + 1 * 16384, nullptr, B1, nullptr, nullptr, nullptr);
    agg_kernel<<<N_NODES / 4, 256, 0, stream>>>(B1, offs, cnt, csr, dis, c1_b, B2);
    gemm_mfma<false, false, false><<<GEMM_GRID, 256, 0, stream>>>(B2, Wt + 2 * 16384, nullptr, B1, nullptr, nullptr, nullptr);
    agg_kernel<<<N_NODES / 4, 256, 0, stream>>>(B1, offs, cnt, csr, dis, c2_b, B2);
    gemm_mfma<true, true, true><<<GEMM_GRID, 256, 0, stream>>>(B2, Wt + 3 * 16384, dec_b1, nullptr, dec_W2, dec_b2, out);
}

// Round 11
// 375.702 us; speedup vs baseline: 1.1945x; 1.0234x over previous
//
#include <hip/hip_runtime.h>

#define N_NODES 100000
#define N_EDGES 1600000
#define NBKT 391          // ceil(100000/256) buckets of 256 nodes
#define BKT_CAP 4608      // padded bucket capacity (avg 4096, +8 sigma)
#define PART_BLOCKS 391   // k_part blocks, 4096 edges each

typedef _Float16 half8 __attribute__((ext_vector_type(8)));
typedef float floatx4 __attribute__((ext_vector_type(4)));

// ---------------- atomic-light CSR build ----------------

__global__ __launch_bounds__(256) void k_part(const int* __restrict__ ei,
                                              const float* __restrict__ ew,
                                              unsigned* __restrict__ cursor,
                                              unsigned* __restrict__ partA,
                                              float* __restrict__ partB) {
    __shared__ unsigned hist[NBKT];
    __shared__ unsigned lrank[NBKT];
    __shared__ unsigned basebuf[NBKT];
    int tid = threadIdx.x;
    int e0 = blockIdx.x * 4096 + tid * 16;
    for (int i = tid; i < NBKT; i += 256) { hist[i] = 0; lrank[i] = 0; }
    __syncthreads();

    unsigned bk[16];
    bool full = (e0 + 16 <= N_EDGES);
    if (full) {
        #pragma unroll
        for (int v = 0; v < 4; v++) {
            int4 c = *(const int4*)(ei + N_EDGES + e0 + v * 4);
            bk[v * 4 + 0] = (unsigned)c.x >> 8;
            bk[v * 4 + 1] = (unsigned)c.y >> 8;
            bk[v * 4 + 2] = (unsigned)c.z >> 8;
            bk[v * 4 + 3] = (unsigned)c.w >> 8;
        }
        #pragma unroll
        for (int i = 0; i < 16; i++) atomicAdd(&hist[bk[i]], 1u);
    } else {
        for (int i = 0; i < 16; i++) {
            if (e0 + i < N_EDGES) {
                bk[i] = (unsigned)ei[N_EDGES + e0 + i] >> 8;
                atomicAdd(&hist[bk[i]], 1u);
            }
        }
    }
    __syncthreads();
    for (int b = tid; b < NBKT; b += 256) {
        unsigned h = hist[b];
        basebuf[b] = h ? atomicAdd(&cursor[b], h) : 0u;
    }
    __syncthreads();

    if (full) {
        #pragma unroll
        for (int v = 0; v < 4; v++) {
            int4 c = *(const int4*)(ei + N_EDGES + e0 + v * 4);
            int4 r = *(const int4*)(ei + e0 + v * 4);
            float4 w = *(const float4*)(ew + e0 + v * 4);
            int cols[4] = {c.x, c.y, c.z, c.w};
            int rows[4] = {r.x, r.y, r.z, r.w};
            float ws4[4] = {w.x, w.y, w.z, w.w};
            #pragma unroll
            for (int i = 0; i < 4; i++) {
                unsigned b = bk[v * 4 + i];
                unsigned rk = atomicAdd(&lrank[b], 1u);
                size_t idx = (size_t)b * BKT_CAP + basebuf[b] + rk;
                partA[idx] = (((unsigned)cols[i] & 255u) << 17) | (unsigned)rows[i];
                partB[idx] = ws4[i];
            }
        }
    } else {
        for (int i = 0; i < 16; i++) {
            if (e0 + i < N_EDGES) {
                int col = ei[N_EDGES + e0 + i];
                int row = ei[e0 + i];
                float wv = ew[e0 + i];
                unsigned b = bk[i];
                unsigned rk = atomicAdd(&lrank[b], 1u);
                size_t idx = (size_t)b * BKT_CAP + basebuf[b] + rk;
                partA[idx] = (((unsigned)col & 255u) << 17) | (unsigned)row;
                partB[idx] = wv;
            }
        }
    }
}

__global__ __launch_bounds__(256) void k_stats(const unsigned* __restrict__ cursor,
                                               const unsigned* __restrict__ partA,
                                               const float* __restrict__ partB,
                                               float* __restrict__ dis,
                                               int* __restrict__ offs,
                                               int* __restrict__ cnt) {
    __shared__ unsigned hist[256];
    __shared__ unsigned sc[256];
    __shared__ float dacc[256];
    int tid = threadIdx.x;
    int j = blockIdx.x;
    int count = (int)cursor[j];
    size_t p0 = (size_t)j * BKT_CAP;
    hist[tid] = 0;
    dacc[tid] = 0.f;
    __syncthreads();
    for (int i = tid; i < count; i += 256) {
        unsigned a = partA[p0 + i];
        float w = partB[p0 + i];
        unsigned cl = (a >> 17) & 255u;
        atomicAdd(&hist[cl], 1u);
        atomicAdd(&dacc[cl], w);
    }
    __syncthreads();
    unsigned myc = hist[tid];
    sc[tid] = myc;
    __syncthreads();
    #pragma unroll
    for (int d = 1; d < 256; d <<= 1) {
        unsigned t = (tid >= d) ? sc[tid - d] : 0u;
        __syncthreads();
        sc[tid] += t;
        __syncthreads();
    }
    int col = j * 256 + tid;
    if (col < N_NODES) {
        dis[col] = rsqrtf(dacc[tid] + 1.0f);
        cnt[col] = (int)myc;
        offs[col] = (int)(p0 + (sc[tid] - myc));
    }
}

// k_scatter: scatter csr entries; also accumulate s_j = sum_e w_e + dis_j^2
__global__ __launch_bounds__(256) void k_scatter(const unsigned* __restrict__ cursor,
                                                 const unsigned* __restrict__ partA,
                                                 const float* __restrict__ partB,
                                                 const int* __restrict__ offs,
                                                 const float* __restrict__ dis,
                                                 unsigned* __restrict__ csr,
                                                 float* __restrict__ svec) {
    __shared__ unsigned cur[256];
    __shared__ float sacc[256];
    int tid = threadIdx.x;
    int j = blockIdx.x;
    int count = (int)cursor[j];
    size_t p0 = (size_t)j * BKT_CAP;
    int col = j * 256 + tid;
    cur[tid] = (col < N_NODES) ? (unsigned)(offs[col] - (int)p0) : 0u;
    sacc[tid] = 0.f;
    __syncthreads();
    for (int i = tid; i < count; i += 256) {
        unsigned a = partA[p0 + i];
        float wv = partB[p0 + i];
        unsigned cl = (a >> 17) & 255u;
        unsigned row = a & 0x1FFFFu;
        unsigned r = atomicAdd(&cur[cl], 1u);
        int colg = j * 256 + (int)cl;
        float w = dis[row] * wv * dis[colg];
        _Float16 hw = (_Float16)w;
        unsigned short hb;
        __builtin_memcpy(&hb, &hw, 2);
        csr[p0 + r] = ((unsigned)hb << 17) | row;
        atomicAdd(&sacc[cl], (float)hw);
    }
    __syncthreads();
    if (col < N_NODES) {
        float d = dis[col];
        svec[col] = sacc[tid] + d * d;
    }
}

// ---------------- weight prep ----------------
// prep_mm: Wc = enc_W2 @ c1_W (f32 accum), stored transposed f16: Wt0[col*128+k]
__global__ __launch_bounds__(256) void prep_mm(const float* __restrict__ W2,
                                               const float* __restrict__ c1W,
                                               _Float16* __restrict__ Wt0) {
    __shared__ float sW[128 * 128];
    int t = threadIdx.x;
    for (int i = t; i < 4096; i += 256) ((float4*)sW)[i] = ((const float4*)c1W)[i];
    __syncthreads();
    int k = blockIdx.x * 2 + (t >> 7);
    int col = t & 127;
    float acc = 0.f;
    #pragma unroll 8
    for (int j = 0; j < 128; j++) acc = fmaf(W2[k * 128 + j], sW[j * 128 + col], acc);
    Wt0[col * 128 + k] = (_Float16)acc;
}

// prep_bb: bb = enc_b2 @ c1_W  (f32, 128)
__global__ __launch_bounds__(128) void prep_bb(const float* __restrict__ b2,
                                               const float* __restrict__ c1W,
                                               float* __restrict__ bb) {
    int c = threadIdx.x;
    float acc = 0.f;
    for (int j = 0; j < 128; j++) acc = fmaf(b2[j], c1W[j * 128 + c], acc);
    bb[c] = acc;
}

// prep_tr: transpose+f16: m0 = c2_W -> Wt1, m1 = dec_W1 -> Wt2
__global__ __launch_bounds__(256) void prep_tr(const float* __restrict__ Wa,
                                               const float* __restrict__ Wb,
                                               _Float16* __restrict__ Wt) {
    int m = blockIdx.x >> 4;
    const float* W = (m == 0) ? Wa : Wb;
    _Float16* o = Wt + (m + 1) * 16384;
    int base = (blockIdx.x & 15) * 1024 + threadIdx.x * 4;
    int col = base >> 7;
    int k0 = base & 127;
    #pragma unroll
    for (int i = 0; i < 4; i++) o[base + i] = (_Float16)W[(k0 + i) * 128 + col];
}

// ---------------- encoder layer 1: [N,16]@[16,128]+b, relu -> f16 ----------------

__global__ __launch_bounds__(256) void enc1_kernel(const float* __restrict__ x,
                                                   const float* __restrict__ W1,
                                                   const float* __restrict__ b1,
                                                   _Float16* __restrict__ out) {
    __shared__ float sX[256 * 17];
    __shared__ float sW[2048];
    __shared__ float sb[128];
    int t = threadIdx.x;
    int base = blockIdx.x * 256;
    for (int i = t; i < 512; i += 256) ((float4*)sW)[i] = ((const float4*)W1)[i];
    if (t < 128) sb[t] = b1[t];
    #pragma unroll
    for (int i = 0; i < 4; i++) {
        int f = i * 1024 + t * 4;
        int row = f >> 4, k = f & 15;
        float4 v = make_float4(0.f, 0.f, 0.f, 0.f);
        if (base + row < N_NODES) v = *(const float4*)(x + (size_t)(base + row) * 16 + k);
        *(float4*)(sX + row * 17 + k) = v;
    }
    __syncthreads();
    int row = base + t;
    if (row >= N_NODES) return;
    float xr[16];
    #pragma unroll
    for (int k = 0; k < 16; k++) xr[k] = sX[t * 17 + k];
    #pragma unroll 4
    for (int cb = 0; cb < 16; cb++) {
        float acc[8];
        #pragma unroll
        for (int jj = 0; jj < 8; jj++) acc[jj] = sb[cb * 8 + jj];
        #pragma unroll
        for (int k = 0; k < 16; k++) {
            float xv = xr[k];
            #pragma unroll
            for (int jj = 0; jj < 8; jj++) acc[jj] = fmaf(xv, sW[k * 128 + cb * 8 + jj], acc[jj]);
        }
        half8 h;
        #pragma unroll
        for (int jj = 0; jj < 8; jj++) h[jj] = (_Float16)fmaxf(acc[jj], 0.f);
        *(half8*)(out + (size_t)row * 128 + cb * 8) = h;
    }
}

// ---------------- f16 MFMA GEMM: [N,128] @ [128,128], 2-phase pipelined ----------------
// SB: bias = svec[row]*bb[col] + bias[col]  (fused GCN bias path)
// DEC: fuse decoder layer2 + softmax from accumulators.

#define GEMM_GRID 522

template <bool BIAS, bool RELU, bool DEC, bool SB>
__global__ __launch_bounds__(256, 2) void gemm_mfma(const _Float16* __restrict__ A,
                                                    const _Float16* __restrict__ Wt,
                                                    const float* __restrict__ bias,
                                                    _Float16* __restrict__ C,
                                                    const float* __restrict__ W2,
                                                    const float* __restrict__ b2,
                                                    float* __restrict__ sm_out,
                                                    const float* __restrict__ svec,
                                                    const float* __restrict__ bbv) {
    __shared__ _Float16 sA[2 * 64 * 128];
    __shared__ _Float16 sE[DEC ? 64 : 64 * 128];
    __shared__ float sW2[DEC ? 256 : 1];
    int t = threadIdx.x;
    int lane = t & 63;
    int w = t >> 6;
    int l15 = lane & 15;
    int l4 = lane >> 4;

    half8 bfrag[8][4];
    #pragma unroll
    for (int n = 0; n < 8; n++)
        #pragma unroll
        for (int kk = 0; kk < 4; kk++)
            bfrag[n][kk] = *(const half8*)(Wt + (n * 16 + l15) * 128 + kk * 32 + l4 * 8);

    float bcol[8];
    if constexpr (BIAS) {
        #pragma unroll
        for (int n = 0; n < 8; n++) bcol[n] = bias[n * 16 + l15];
    }
    float bbcol[8];
    if constexpr (SB) {
        #pragma unroll
        for (int n = 0; n < 8; n++) bbcol[n] = bbv[n * 16 + l15];
    }
    float b20 = 0.f, b21 = 0.f;
    if constexpr (DEC) {
        if (t < 256) sW2[t] = W2[t];
        b20 = b2[0]; b21 = b2[1];
    }

    auto STAGE = [&](int buf, int tile) {
        const _Float16* Ag = A + (size_t)tile * 64 * 128;
        #pragma unroll
        for (int i = 0; i < 4; i++) {
            int c = i * 256 + t;
            int row = c >> 4;
            int g = (c & 15) ^ (row & 7);
            const _Float16* src = Ag + row * 128 + g * 8;
            __builtin_amdgcn_global_load_lds(
                (const __attribute__((address_space(1))) void*)src,
                (__attribute__((address_space(3))) void*)(sA + buf * 8192 + (size_t)(i * 256 + w * 64) * 8),
                16, 0, 0);
        }
    };

    const int NT = (N_NODES + 63) / 64;
    int cur = 0;
    STAGE(0, blockIdx.x);

    for (int tile = blockIdx.x; tile < NT; tile += GEMM_GRID) {
        int nx = tile + GEMM_GRID;
        if (nx < NT) {
            STAGE(cur ^ 1, nx);
            asm volatile("s_waitcnt vmcnt(4)" ::: "memory");
        } else {
            asm volatile("s_waitcnt vmcnt(0)" ::: "memory");
        }
        __builtin_amdgcn_s_barrier();
        asm volatile("" ::: "memory");

        const _Float16* sAc = sA + cur * 8192;

        floatx4 acc[8];
        #pragma unroll
        for (int n = 0; n < 8; n++) acc[n] = (floatx4)(0.f);

        #pragma unroll
        for (int kk = 0; kk < 4; kk++) {
            int rloc = w * 16 + l15;
            int cl = kk * 4 + l4;
            int s = cl ^ (rloc & 7);
            half8 af = *(const half8*)(sAc + rloc * 128 + s * 8);
            #pragma unroll
            for (int n = 0; n < 8; n++)
                acc[n] = __builtin_amdgcn_mfma_f32_16x16x32_f16(af, bfrag[n][kk], acc[n], 0, 0, 0);
        }

        size_t base_row = (size_t)tile * 64;
        float s4[4];
        if constexpr (SB) {
            #pragma unroll
            for (int r = 0; r < 4; r++) {
                int rr = (int)base_row + w * 16 + l4 * 4 + r;
                s4[r] = (rr < N_NODES) ? svec[rr] : 0.f;
            }
        }
        if constexpr (DEC) {
            #pragma unroll
            for (int r = 0; r < 4; r++) {
                float p0 = 0.f, p1 = 0.f;
                #pragma unroll
                for (int n = 0; n < 8; n++) {
                    float v = acc[n][r];
                    if constexpr (BIAS) v += bcol[n];
                    if constexpr (RELU) v = fmaxf(v, 0.f);
                    int ch = n * 16 + l15;
                    p0 = fmaf(v, sW2[ch * 2 + 0], p0);
                    p1 = fmaf(v, sW2[ch * 2 + 1], p1);
                }
                #pragma unroll
                for (int m = 1; m < 16; m <<= 1) {
                    p0 += __shfl_xor(p0, m, 64);
                    p1 += __shfl_xor(p1, m, 64);
                }
                size_t grow = base_row + w * 16 + l4 * 4 + r;
                if (l15 == 0 && grow < N_NODES) {
                    float z0 = p0 + b20, z1 = p1 + b21;
                    float mx = fmaxf(z0, z1);
                    float e0 = expf(z0 - mx), e1 = expf(z1 - mx);
                    float si = 1.f / (e0 + e1);
                    *(float2*)(sm_out + grow * 2) = make_float2(e0 * si, e1 * si);
                }
            }
            __builtin_amdgcn_s_barrier();
            asm volatile("" ::: "memory");
        } else {
            #pragma unroll
            for (int n = 0; n < 8; n++) {
                #pragma unroll
                for (int r = 0; r < 4; r++) {
                    float v = acc[n][r];
                    if constexpr (SB) v += s4[r] * bbcol[n];
                    if constexpr (BIAS) v += bcol[n];
                    if constexpr (RELU) v = fmaxf(v, 0.f);
                    int row = w * 16 + l4 * 4 + r;
                    sE[row * 128 + n * 16 + l15] = (_Float16)v;
                }
            }
            __builtin_amdgcn_s_barrier();
            asm volatile("" ::: "memory");
            #pragma unroll
            for (int i = 0; i < 4; i++) {
                int c = i * 256 + t;
                int row = c >> 4;
                if (base_row + row < N_NODES) {
                    *(float4*)((char*)C + (base_row + row) * 256 + (c & 15) * 16) =
                        *(const float4*)((const char*)sE + (size_t)c * 16);
                }
            }
        }
        cur ^= 1;
    }
}

// ---------------- GCN aggregation (pure linear: out = sum w*m[row] + dd*m[j]) ----------------

__global__ __launch_bounds__(256) void agg_kernel(const _Float16* __restrict__ m,
                                                  const int* __restrict__ offs,
                                                  const int* __restrict__ cnt,
                                                  const unsigned* __restrict__ csr,
                                                  const float* __restrict__ dis,
                                                  _Float16* __restrict__ out) {
    int wave = threadIdx.x >> 6;
    int lane = threadIdx.x & 63;
    int g = lane >> 4;
    int q = lane & 15;
    int j = blockIdx.x * 4 + wave;
    if (j >= N_NODES) return;
    int s = offs[j];
    int num = cnt[j];

    float acc[8];
    if (g == 0) {
        float d = dis[j];
        float dd = d * d;
        half8 mv = *(const half8*)(m + (size_t)j * 128 + q * 8);
        #pragma unroll
        for (int i = 0; i < 8; i++) acc[i] = dd * (float)mv[i];
    } else {
        #pragma unroll
        for (int i = 0; i < 8; i++) acc[i] = 0.f;
    }

    int e = 0;
    for (; e + 16 <= num; e += 16) {
        unsigned u0 = csr[s + e + g];
        unsigned u1 = csr[s + e + 4 + g];
        unsigned u2 = csr[s + e + 8 + g];
        unsigned u3 = csr[s + e + 12 + g];
        half8 r0 = *(const half8*)(m + (size_t)(u0 & 0x1FFFF) * 128 + q * 8);
        half8 r1 = *(const half8*)(m + (size_t)(u1 & 0x1FFFF) * 128 + q * 8);
        half8 r2 = *(const half8*)(m + (size_t)(u2 & 0x1FFFF) * 128 + q * 8);
        half8 r3 = *(const half8*)(m + (size_t)(u3 & 0x1FFFF) * 128 + q * 8);
        unsigned short b0 = (unsigned short)(u0 >> 17), b1 = (unsigned short)(u1 >> 17);
        unsigned short b2 = (unsigned short)(u2 >> 17), b3 = (unsigned short)(u3 >> 17);
        _Float16 h0, h1, h2, h3;
        __builtin_memcpy(&h0, &b0, 2); __builtin_memcpy(&h1, &b1, 2);
        __builtin_memcpy(&h2, &b2, 2); __builtin_memcpy(&h3, &b3, 2);
        float w0 = (float)h0, w1 = (float)h1, w2 = (float)h2, w3 = (float)h3;
        #pragma unroll
        for (int i = 0; i < 8; i++) acc[i] = fmaf(w0, (float)r0[i], acc[i]);
        #pragma unroll
        for (int i = 0; i < 8; i++) acc[i] = fmaf(w1, (float)r1[i], acc[i]);
        #pragma unroll
        for (int i = 0; i < 8; i++) acc[i] = fmaf(w2, (float)r2[i], acc[i]);
        #pragma unroll
        for (int i = 0; i < 8; i++) acc[i] = fmaf(w3, (float)r3[i], acc[i]);
    }
    for (; e < num; e += 4) {
        if (e + g < num) {
            unsigned u0 = csr[s + e + g];
            unsigned short b0 = (unsigned short)(u0 >> 17);
            _Float16 h0;
            __builtin_memcpy(&h0, &b0, 2);
            half8 r0 = *(const half8*)(m + (size_t)(u0 & 0x1FFFF) * 128 + q * 8);
            float w0 = (float)h0;
            #pragma unroll
            for (int i = 0; i < 8; i++) acc[i] = fmaf(w0, (float)r0[i], acc[i]);
        }
    }

    #pragma unroll
    for (int i = 0; i < 8; i++) {
        acc[i] += __shfl_xor(acc[i], 16, 64);
        acc[i] += __shfl_xor(acc[i], 32, 64);
    }

    if (g == 0) {
        half8 o;
        #pragma unroll
        for (int i = 0; i < 8; i++) o[i] = (_Float16)acc[i];
        *(half8*)(out + (size_t)j * 128 + q * 8) = o;
    }
}

// ---------------- launch ----------------

extern "C" void kernel_launch(void* const* d_in, const int* in_sizes, int n_in,
                              void* d_out, int out_size, void* d_ws, size_t ws_size,
                              hipStream_t stream) {
    const float* x      = (const float*)d_in[0];
    const int*   ei     = (const int*)d_in[1];
    const float* ew     = (const float*)d_in[2];
    const float* enc_W1 = (const float*)d_in[3];
    const float* enc_b1 = (const float*)d_in[4];
    const float* enc_W2 = (const float*)d_in[5];
    const float* enc_b2 = (const float*)d_in[6];
    const float* c1_W   = (const float*)d_in[7];
    const float* c1_b   = (const float*)d_in[8];
    const float* c2_W   = (const float*)d_in[9];
    const float* c2_b   = (const float*)d_in[10];
    const float* dec_W1 = (const float*)d_in[11];
    const float* dec_b1 = (const float*)d_in[12];
    const float* dec_W2 = (const float*)d_in[13];
    const float* dec_b2 = (const float*)d_in[14];
    float* out = (float*)d_out;

    char* ws = (char*)d_ws;
    // part buffers alias B1 (dead before enc1 writes B1)
    unsigned* partA = (unsigned*)(ws);                       // 7,206,912
    float*    partB = (float*)(ws + 7206912);                // 7,206,912 (ends 14,413,824)
    _Float16* B1 = (_Float16*)(ws);                          // 25,600,000
    _Float16* B2 = (_Float16*)(ws + 25600000);               // 25,600,000
    _Float16* Wt = (_Float16*)(ws + 51200000);               // 131,072 (Wt0/Wt1/Wt2)
    unsigned* cursor = (unsigned*)(ws + 51331072);           // 2,048
    float* dis     = (float*)(ws + 51333120);                // 400,000
    int*   offs    = (int*)  (ws + 51733120);                // 400,000
    int*   cnt     = (int*)  (ws + 52133120);                // 400,000
    unsigned* csr  = (unsigned*)(ws + 52533120);             // 7,206,912
    float* svec    = (float*)(ws + 59740032);                // 400,000
    float* bb      = (float*)(ws + 60140032);                // 512
    // end ~60.1 MB

    hipMemsetAsync(cursor, 0, 2048, stream);

    k_part<<<PART_BLOCKS, 256, 0, stream>>>(ei, ew, cursor, partA, partB);
    k_stats<<<NBKT, 256, 0, stream>>>(cursor, partA, partB, dis, offs, cnt);
    k_scatter<<<NBKT, 256, 0, stream>>>(cursor, partA, partB, offs, dis, csr, svec);

    prep_mm<<<64, 256, 0, stream>>>(enc_W2, c1_W, Wt);
    prep_bb<<<1, 128, 0, stream>>>(enc_b2, c1_W, bb);
    prep_tr<<<32, 256, 0, stream>>>(c2_W, dec_W1, Wt);
    enc1_kernel<<<(N_NODES + 255) / 256, 256, 0, stream>>>(x, enc_W1, enc_b1, B1);

    // conv1: agg(h1) -> gemm with Wc = enc_W2@c1_W, bias = s*bb + c1_b, relu
    agg_kernel<<<N_NODES / 4, 256, 0, stream>>>(B1, offs, cnt, csr, dis, B2);
    gemm_mfma<true, true, false, true><<<GEMM_GRID, 256, 0, stream>>>(
        B2, Wt + 0 * 16384, c1_b, B1, nullptr, nullptr, nullptr, svec, bb);
    // conv2: agg(o1) -> gemm c2_W + c2_b, relu
    agg_kernel<<<N_NODES / 4, 256, 0, stream>>>(B1, offs, cnt, csr, dis, B2);
    gemm_mfma<true, true, false, false><<<GEMM_GRID, 256, 0, stream>>>(
        B2, Wt + 1 * 16384, c2_b, B1, nullptr, nullptr, nullptr, nullptr, nullptr);
    // decoder: dec_W1 + b, relu; fused dec_W2 + softmax
    gemm_mfma<true, true, true, false><<<GEMM_GRID, 256, 0, stream>>>(
        B1, Wt + 2 * 16384, dec_b1, nullptr, dec_W2, dec_b2, out, nullptr, nullptr);
}